// Round 4
// baseline (76.227 us; speedup 1.0000x reference)
//
#include <hip/hip_runtime.h>

#define N 16384
#define CHUNKS 16
#define CHUNK 1024   // N / CHUNKS
#define BLK 256

typedef float v2f __attribute__((ext_vector_type(2)));

// sigma_ij = 1/(1 + ea_i*eb_j), ea=2^(C*x_i), eb=2^(-C*x_j), C=10*log2(e).
// Batched rcp: sum_i 1/p_i = (sum_i prod_{k!=i} p_k)/prod_k p_k -> 1 rcp / 8 pairs.
// P clamped to [1, 2^15] so 8-products stay finite; clamp error <= 2^-15/pair.
// eb read at wave-uniform addresses -> SGPRs (s_load), fed to v_pk_fma_f32 as
// the single scalar source. All pair math forced to VOP3P packed fp32.

__device__ __forceinline__ v2f pk_fma_s(v2f va, v2f sb, v2f vc) {
    v2f d;
    asm("v_pk_fma_f32 %0, %1, %2, %3" : "=v"(d) : "v"(va), "s"(sb), "v"(vc));
    return d;
}
__device__ __forceinline__ v2f pk_fma(v2f a, v2f b, v2f c) {
    v2f d;
    asm("v_pk_fma_f32 %0, %1, %2, %3" : "=v"(d) : "v"(a), "v"(b), "v"(c));
    return d;
}
__device__ __forceinline__ v2f pk_mul(v2f a, v2f b) {
    v2f d;
    asm("v_pk_mul_f32 %0, %1, %2" : "=v"(d) : "v"(a), "v"(b));
    return d;
}
__device__ __forceinline__ v2f pk_add(v2f a, v2f b) {
    v2f d;
    asm("v_pk_add_f32 %0, %1, %2" : "=v"(d) : "v"(a), "v"(b));
    return d;
}
__device__ __forceinline__ v2f pmin2(v2f a, v2f b) {
    return __builtin_elementwise_min(a, b);   // 2x v_min_f32 (no packed f32 min)
}

__global__ __launch_bounds__(256) void prep_eb(
    const float* __restrict__ pred, const float* __restrict__ target,
    float* __restrict__ ebg) {
    const int t = blockIdx.x * 256 + threadIdx.x;       // 0 .. 2N-1
    const float C = 14.426950408889634f;                // 10 * log2(e)
    const float x = (t < N) ? pred[t] : target[t - N];
    ebg[t] = __builtin_amdgcn_exp2f(-C * x);
}

__global__ __launch_bounds__(BLK) void soft_rank_partial(
    const float* __restrict__ pred, const float* __restrict__ target,
    const float* __restrict__ ebg, float* __restrict__ partials) {
    const int arr = blockIdx.z;                         // 0 = pred, 1 = target
    const float* __restrict__ x = arr ? target : pred;
    const int i = blockIdx.x * BLK + threadIdx.x;

    const float C = 14.426950408889634f;
    const float ea = __builtin_amdgcn_exp2f(C * x[i]);  // EA_i
    const v2f ea2  = {ea, ea};
    const v2f one2 = {1.0f, 1.0f};
    const v2f cl2  = {32768.0f, 32768.0f};              // 2^15 clamp

    // wave-uniform eb pointer for this chunk
    const v2f* __restrict__ ebp = (const v2f*)(ebg + arr * N + blockIdx.y * CHUNK);

    v2f acc = {0.f, 0.f};
    #pragma unroll 2
    for (int t = 0; t < CHUNK / 16; ++t) {
        const v2f* __restrict__ e = ebp + t * 8;        // 16 j's per iteration
        v2f P0 = pmin2(pk_fma_s(ea2, e[0], one2), cl2);
        v2f P1 = pmin2(pk_fma_s(ea2, e[1], one2), cl2);
        v2f P2 = pmin2(pk_fma_s(ea2, e[2], one2), cl2);
        v2f P3 = pmin2(pk_fma_s(ea2, e[3], one2), cl2);
        v2f P4 = pmin2(pk_fma_s(ea2, e[4], one2), cl2);
        v2f P5 = pmin2(pk_fma_s(ea2, e[5], one2), cl2);
        v2f P6 = pmin2(pk_fma_s(ea2, e[6], one2), cl2);
        v2f P7 = pmin2(pk_fma_s(ea2, e[7], one2), cl2);

        v2f S01 = pk_add(P0, P1), Q01 = pk_mul(P0, P1);
        v2f S23 = pk_add(P2, P3), Q23 = pk_mul(P2, P3);
        v2f S45 = pk_add(P4, P5), Q45 = pk_mul(P4, P5);
        v2f S67 = pk_add(P6, P7), Q67 = pk_mul(P6, P7);
        v2f Q0123 = pk_mul(Q01, Q23), Q4567 = pk_mul(Q45, Q67);
        v2f PP = pk_mul(Q0123, Q4567);                  // <= 2^120, finite
        v2f N1 = pk_fma(Q01, S23, pk_mul(Q23, S01));    // sum of 3-prods (0..3)
        v2f N2 = pk_fma(Q45, S67, pk_mul(Q67, S45));    // (4..7)
        v2f NUM = pk_fma(Q0123, N2, pk_mul(Q4567, N1)); // sum_i prod_{k!=i} p_k
        v2f R = { __builtin_amdgcn_rcpf(PP.x), __builtin_amdgcn_rcpf(PP.y) };
        acc = pk_fma(NUM, R, acc);
    }
    partials[((size_t)(arr * CHUNKS + blockIdx.y)) * N + i] = acc.x + acc.y;
}

// ranks from partials + per-block f64 moment partials (deterministic tree).
__global__ __launch_bounds__(256) void rank_moments(
    const float* __restrict__ partials, double* __restrict__ mom) {
    const int tid = threadIdx.x;
    const int i   = blockIdx.x * 256 + tid;             // 0..N-1
    float pr = 1.0f, tr = 1.0f;                         // the "+1.0" in soft_rank
    #pragma unroll
    for (int c = 0; c < CHUNKS; ++c) {
        pr += partials[(size_t)c * N + i];
        tr += partials[(size_t)(CHUNKS + c) * N + i];
    }
    double p = (double)pr, t = (double)tr;

    __shared__ double sh[5][256];
    sh[0][tid] = p; sh[1][tid] = t; sh[2][tid] = p * p;
    sh[3][tid] = t * t; sh[4][tid] = p * t;
    __syncthreads();
    for (int s = 128; s > 0; s >>= 1) {
        if (tid < s) {
            #pragma unroll
            for (int k = 0; k < 5; ++k) sh[k][tid] += sh[k][tid + s];
        }
        __syncthreads();
    }
    if (tid == 0) {
        #pragma unroll
        for (int k = 0; k < 5; ++k) mom[blockIdx.x * 5 + k] = sh[k][0];
    }
}

__global__ void final_corr(const double* __restrict__ mom, float* __restrict__ out) {
    const int l = threadIdx.x;                          // one wave; 64 mom rows
    double v[5];
    #pragma unroll
    for (int k = 0; k < 5; ++k) v[k] = mom[l * 5 + k];
    #pragma unroll
    for (int off = 32; off > 0; off >>= 1) {
        #pragma unroll
        for (int k = 0; k < 5; ++k) v[k] += __shfl_down(v[k], off);
    }
    if (l == 0) {
        const double n  = (double)N;
        const double mp = v[0] / n;
        const double mt = v[1] / n;
        const double cov  = v[4] / n - mp * mt;
        const double varp = v[2] / n - mp * mp;
        const double vart = v[3] / n - mt * mt;
        const double corr = cov / (sqrt(varp + 1e-8) * sqrt(vart + 1e-8));
        out[0] = (float)(1.0 - corr);
    }
}

extern "C" void kernel_launch(void* const* d_in, const int* in_sizes, int n_in,
                              void* d_out, int out_size, void* d_ws, size_t ws_size,
                              hipStream_t stream) {
    const float* pred   = (const float*)d_in[0];
    const float* target = (const float*)d_in[1];
    float* out = (float*)d_out;

    // ws: partials[2*CHUNKS*N] f32 (2 MB) | ebg[2*N] f32 (128 KB) | mom[64*5] f64
    float*  partials = (float*)d_ws;
    float*  ebg      = partials + (size_t)2 * CHUNKS * N;
    double* mom      = (double*)(ebg + 2 * N);

    prep_eb<<<(2 * N) / 256, 256, 0, stream>>>(pred, target, ebg);
    dim3 gridA(N / BLK, CHUNKS, 2);
    soft_rank_partial<<<gridA, BLK, 0, stream>>>(pred, target, ebg, partials);
    rank_moments<<<N / 256, 256, 0, stream>>>(partials, mom);
    final_corr<<<1, 64, 0, stream>>>(mom, out);
}

// Round 5
// 28.266 us; speedup vs baseline: 2.6968x; 2.6968x over previous
//
#include <hip/hip_runtime.h>

#define N 16384
#define M 128          // Fourier modes
#define JB 32          // j-blocks in phase 1
#define JSL 512        // j's per block (N/JB)

// rank_i = 1 + N/2 + 0.5*sum_j tanh(5*(x_j - x_i))
// tanh(5d) = d/L + sum_{m=1..M} beta_m sin(pi*m*d/L),  L=8,
//   beta_m = pi/(5*L*sinh(pi^2*m/(10*L)))        (exact periodized-sech^2 series)
// valid |d| <= 2L-1 = 15 >> max|x_i - x_j| (~8); tail < 2e-7 per pair.
// sin(w(xj-xi)) separates -> per-frequency sums S_m = sum_j cos(w_m x_j),
// T_m = sum_j sin(w_m x_j); then rank_i needs only M sin/cos of x_i.
// v_sin/v_cos take REVOLUTIONS: rev = m*x/(2L) = m*x*0.0625, fract-reduced.

__global__ __launch_bounds__(256) void freq_partials(
    const float* __restrict__ pred, const float* __restrict__ target,
    float* __restrict__ ps, float* __restrict__ pc, float* __restrict__ px) {
  const int a   = blockIdx.y;                 // 0 = pred, 1 = target
  const float* __restrict__ x = a ? target : pred;
  const int jb  = blockIdx.x;                 // 0..JB-1
  const int tid = threadIdx.x;
  __shared__ float xs[JSL];
  xs[tid]       = x[jb*JSL + tid];
  xs[tid + 256] = x[jb*JSL + 256 + tid];
  __syncthreads();

  const int   mi   = tid & 127;               // m-1
  const int   half = tid >> 7;
  const float mf   = (float)(mi + 1) * 0.0625f;   // m/(2L)
  const float* __restrict__ xh = xs + half * 256;
  float ss = 0.f, cc = 0.f;
  #pragma unroll 4
  for (int k = 0; k < 256; ++k) {
    float rev = __builtin_amdgcn_fractf(mf * xh[k]);
    ss += __builtin_amdgcn_sinf(rev);
    cc += __builtin_amdgcn_cosf(rev);
  }
  const int idx = (a*JB + jb)*256 + tid;      // slot = half*128 + (m-1)
  ps[idx] = ss;
  pc[idx] = cc;

  if (tid < 64) {                             // block x-sum (for the d/L linear term)
    float t = 0.f;
    #pragma unroll
    for (int k = 0; k < 8; ++k) t += xs[tid + 64*k];
    #pragma unroll
    for (int off = 32; off; off >>= 1) t += __shfl_down(t, off);
    if (tid == 0) px[a*JB + jb] = t;
  }
}

__global__ __launch_bounds__(256) void rank_moments(
    const float* __restrict__ pred, const float* __restrict__ target,
    const float* __restrict__ ps, const float* __restrict__ pc,
    const float* __restrict__ px, double* __restrict__ mom) {
  const int tid = threadIdx.x;
  const int i   = blockIdx.x*256 + tid;

  __shared__ float sCT[2][M];   // 0.5*beta_m*T_m   (multiplies cos(w_m x_i))
  __shared__ float sCS[2][M];   // -0.5*beta_m*S_m  (multiplies sin(w_m x_i))
  __shared__ float sSx[2];
  {
    const int a = tid >> 7, mi = tid & 127;
    float Tsum = 0.f, Csum = 0.f;
    #pragma unroll 4
    for (int jb = 0; jb < JB; ++jb) {
      const int base = (a*JB + jb)*256 + mi;
      Tsum += ps[base] + ps[base + 128];      // both j-halves
      Csum += pc[base] + pc[base + 128];
    }
    const float t = 0.123370055013617f * (float)(mi + 1);  // pi^2*m/(10L)
    const float e = __expf(t);
    const float beta = 3.14159265358979f / (20.0f * (e - 1.0f/e)); // pi/(40 sinh t)
    sCT[a][mi] =  0.5f * beta * Tsum;
    sCS[a][mi] = -0.5f * beta * Csum;
    if (mi == 0) {                            // tid==0 and tid==128
      float s = 0.f;
      for (int jb = 0; jb < JB; ++jb) s += px[a*JB + jb];
      sSx[a] = s;
    }
  }
  __syncthreads();

  const float xp = pred[i], xt = target[i];
  float accp = 0.f, acct = 0.f;
  #pragma unroll 8
  for (int m = 1; m <= M; ++m) {
    const float mf = (float)m * 0.0625f;
    float rp = __builtin_amdgcn_fractf(mf * xp);
    accp = fmaf(__builtin_amdgcn_cosf(rp), sCT[0][m-1], accp);
    accp = fmaf(__builtin_amdgcn_sinf(rp), sCS[0][m-1], accp);
    float rt = __builtin_amdgcn_fractf(mf * xt);
    acct = fmaf(__builtin_amdgcn_cosf(rt), sCT[1][m-1], acct);
    acct = fmaf(__builtin_amdgcn_sinf(rt), sCS[1][m-1], acct);
  }
  const float base = 8193.0f;                 // 1 + N/2
  const float pr = base + 0.0625f * (sSx[0] - 16384.0f * xp) + accp;  // 1/(2L)=0.0625
  const float tr = base + 0.0625f * (sSx[1] - 16384.0f * xt) + acct;

  double p = (double)pr, t2 = (double)tr;
  __shared__ double sh[5][256];
  sh[0][tid] = p;      sh[1][tid] = t2;
  sh[2][tid] = p * p;  sh[3][tid] = t2 * t2;  sh[4][tid] = p * t2;
  __syncthreads();
  for (int s = 128; s > 0; s >>= 1) {
    if (tid < s) {
      #pragma unroll
      for (int k = 0; k < 5; ++k) sh[k][tid] += sh[k][tid + s];
    }
    __syncthreads();
  }
  if (tid == 0) {
    #pragma unroll
    for (int k = 0; k < 5; ++k) mom[blockIdx.x * 5 + k] = sh[k][0];
  }
}

__global__ void final_corr(const double* __restrict__ mom, float* __restrict__ out) {
  const int l = threadIdx.x;                  // one wave; 64 mom rows
  double v[5];
  #pragma unroll
  for (int k = 0; k < 5; ++k) v[k] = mom[l * 5 + k];
  #pragma unroll
  for (int off = 32; off > 0; off >>= 1) {
    #pragma unroll
    for (int k = 0; k < 5; ++k) v[k] += __shfl_down(v[k], off);
  }
  if (l == 0) {
    const double n  = (double)N;
    const double mp = v[0] / n;
    const double mt = v[1] / n;
    const double cov  = v[4] / n - mp * mt;
    const double varp = v[2] / n - mp * mp;
    const double vart = v[3] / n - mt * mt;
    const double corr = cov / (sqrt(varp + 1e-8) * sqrt(vart + 1e-8));
    out[0] = (float)(1.0 - corr);
  }
}

extern "C" void kernel_launch(void* const* d_in, const int* in_sizes, int n_in,
                              void* d_out, int out_size, void* d_ws, size_t ws_size,
                              hipStream_t stream) {
  const float* pred   = (const float*)d_in[0];
  const float* target = (const float*)d_in[1];
  float* out = (float*)d_out;

  // ws: mom[64*5] f64 | ps[2*JB*256] f32 | pc[2*JB*256] f32 | px[64] f32  (~134 KB)
  double* mom = (double*)d_ws;
  float*  ps  = (float*)(mom + 64 * 5);
  float*  pc  = ps + 2 * JB * 256;
  float*  px  = pc + 2 * JB * 256;

  freq_partials<<<dim3(JB, 2), 256, 0, stream>>>(pred, target, ps, pc, px);
  rank_moments<<<N / 256, 256, 0, stream>>>(pred, target, ps, pc, px, mom);
  final_corr<<<1, 64, 0, stream>>>(mom, out);
}

// Round 6
// 26.142 us; speedup vs baseline: 2.9159x; 1.0812x over previous
//
#include <hip/hip_runtime.h>

#define N 16384
#define M 64           // Fourier modes (lane = m-1)
#define JB 128         // j-blocks per array in K1
#define JSL 128        // j's per K1 block
#define K2B 128        // K2 blocks
#define K2I 128        // i's per K2 block

// rank_i = 1 + N/2 + 0.5*sum_j tanh(5*(x_j - x_i))
// tanh(5d) = d/L + sum_m beta_m sin(pi*m*d/L), L=8, beta_m = pi/(40*sinh(pi^2 m/80))
// sin separates -> S_m = sum_j sin(w_m x_j), C_m = sum_j cos(w_m x_j) once, then
// rank_i = 8193 + (Sx - N x_i)/16 + sum_m 0.5*beta_m*(cos(w_m x_i) S_m - sin(w_m x_i) C_m)
// v_sin/v_cos take REVOLUTIONS: rev = fract(m*x/16).

__global__ __launch_bounds__(256) void freq_partials(
    const float* __restrict__ pred, const float* __restrict__ target,
    float* __restrict__ ps, float* __restrict__ pc, float* __restrict__ px,
    int* __restrict__ counter) {
  const int a   = blockIdx.y;                // 0 = pred, 1 = target
  const float* __restrict__ x = a ? target : pred;
  const int jb  = blockIdx.x;
  const int tid = threadIdx.x;
  if (a == 0 && jb == 0 && tid == 0) *counter = 0;   // reset finalize counter for K2

  __shared__ float xs[JSL];
  __shared__ float shS[4][M];
  __shared__ float shC[4][M];
  if (tid < JSL) xs[tid] = x[jb * JSL + tid];
  __syncthreads();

  const int   w    = tid >> 6;               // wave 0..3 -> 32 j's each
  const int   lane = tid & 63;               // lane = m-1
  const float mf   = (float)(lane + 1) * 0.0625f;   // m/(2L)
  float ss = 0.f, cc = 0.f;
  #pragma unroll
  for (int k = 0; k < 32; ++k) {
    float rev = __builtin_amdgcn_fractf(mf * xs[w * 32 + k]);
    ss += __builtin_amdgcn_sinf(rev);
    cc += __builtin_amdgcn_cosf(rev);
  }
  shS[w][lane] = ss;
  shC[w][lane] = cc;
  __syncthreads();
  if (w == 0) {
    float S = (shS[0][lane] + shS[1][lane]) + (shS[2][lane] + shS[3][lane]);
    float C = (shC[0][lane] + shC[1][lane]) + (shC[2][lane] + shC[3][lane]);
    ps[(a * JB + jb) * M + lane] = S;
    pc[(a * JB + jb) * M + lane] = C;
  } else if (w == 1) {                       // block x-sum for the linear term
    float t = xs[lane] + xs[lane + 64];
    #pragma unroll
    for (int off = 32; off; off >>= 1) t += __shfl_down(t, off);
    if (lane == 0) px[a * JB + jb] = t;
  }
}

__global__ __launch_bounds__(256) void rank_corr(
    const float* __restrict__ pred, const float* __restrict__ target,
    const float* __restrict__ ps, const float* __restrict__ pc,
    const float* __restrict__ px, double* __restrict__ mom,
    int* __restrict__ counter, float* __restrict__ out) {
  const int tid = threadIdx.x;

  __shared__ float2 sCTS[2][M];   // .x = 0.5*beta*S_m (×cos),  .y = -0.5*beta*C_m (×sin)
  __shared__ float  shC[2][M], shT[2][M];
  __shared__ float  sSx[2];

  {                                          // reduce K1 partials (all L2-resident)
    const int grp = tid >> 7;                // 0: cos sums, 1: sin sums
    const int aa  = (tid >> 6) & 1;
    const int mm  = tid & 63;
    const float* __restrict__ src = grp ? ps : pc;
    float s = 0.f;
    #pragma unroll 8
    for (int jb = 0; jb < JB; ++jb) s += src[(aa * JB + jb) * M + mm];
    if (grp) shT[aa][mm] = s; else shC[aa][mm] = s;
    if (tid < 2) {
      float t = 0.f;
      #pragma unroll 8
      for (int jb = 0; jb < JB; ++jb) t += px[tid * JB + jb];
      sSx[tid] = t;
    }
  }
  __syncthreads();
  if (tid < 2 * M) {
    const int aa = tid >> 6, mm = tid & 63;
    const float t    = 0.123370055013617f * (float)(mm + 1);   // pi^2*m/(10L)
    const float e    = __expf(t);
    const float beta = 3.14159265358979f / (20.0f * (e - 1.0f / e)); // pi/(40 sinh t)
    sCTS[aa][mm] = make_float2(0.5f * beta * shT[aa][mm],
                               -0.5f * beta * shC[aa][mm]);
  }
  __syncthreads();

  const int a  = tid >> 7;                   // 0 = pred, 1 = target
  const int li = tid & 127;
  const int i  = blockIdx.x * K2I + li;
  const float xi = (a ? target : pred)[i];
  float acc = 0.f;
  #pragma unroll
  for (int m = 1; m <= M; ++m) {
    const float2 c = sCTS[a][m - 1];
    float rev = __builtin_amdgcn_fractf((float)m * 0.0625f * xi);
    acc = fmaf(__builtin_amdgcn_cosf(rev), c.x, acc);
    acc = fmaf(__builtin_amdgcn_sinf(rev), c.y, acc);
  }
  const float rank = 8193.0f + 0.0625f * (sSx[a] - 16384.0f * xi) + acc;

  __shared__ float shP[K2I], shQ[K2I];
  if (a == 0) shP[li] = rank; else shQ[li] = rank;
  __syncthreads();

  __shared__ double sh[5][K2I];
  if (tid < K2I) {
    double p = (double)shP[tid], t = (double)shQ[tid];
    sh[0][tid] = p;     sh[1][tid] = t;
    sh[2][tid] = p * p; sh[3][tid] = t * t; sh[4][tid] = p * t;
  }
  __syncthreads();
  for (int s = K2I / 2; s > 0; s >>= 1) {
    if (tid < s) {
      #pragma unroll
      for (int k = 0; k < 5; ++k) sh[k][tid] += sh[k][tid + s];
    }
    __syncthreads();
  }

  __shared__ int lastFlag;
  if (tid == 0) {
    #pragma unroll
    for (int k = 0; k < 5; ++k) mom[blockIdx.x * 5 + k] = sh[k][0];
    __threadfence();
    int prev = __hip_atomic_fetch_add(counter, 1, __ATOMIC_ACQ_REL,
                                      __HIP_MEMORY_SCOPE_AGENT);
    lastFlag = (prev == K2B - 1);
  }
  __syncthreads();
  if (lastFlag) {                            // deterministic: fixed-order tree
    if (tid < K2B) {
      #pragma unroll
      for (int k = 0; k < 5; ++k)
        sh[k][tid] = __hip_atomic_load(&mom[tid * 5 + k], __ATOMIC_RELAXED,
                                       __HIP_MEMORY_SCOPE_AGENT);
    }
    __syncthreads();
    for (int s = K2B / 2; s > 0; s >>= 1) {
      if (tid < s) {
        #pragma unroll
        for (int k = 0; k < 5; ++k) sh[k][tid] += sh[k][tid + s];
      }
      __syncthreads();
    }
    if (tid == 0) {
      const double n  = (double)N;
      const double mp = sh[0][0] / n;
      const double mt = sh[1][0] / n;
      const double cov  = sh[4][0] / n - mp * mt;
      const double varp = sh[2][0] / n - mp * mp;
      const double vart = sh[3][0] / n - mt * mt;
      const double corr = cov / (sqrt(varp + 1e-8) * sqrt(vart + 1e-8));
      out[0] = (float)(1.0 - corr);
    }
  }
}

extern "C" void kernel_launch(void* const* d_in, const int* in_sizes, int n_in,
                              void* d_out, int out_size, void* d_ws, size_t ws_size,
                              hipStream_t stream) {
  const float* pred   = (const float*)d_in[0];
  const float* target = (const float*)d_in[1];
  float* out = (float*)d_out;

  // ws: mom[K2B*5] f64 | ps[2*JB*M] f32 | pc[2*JB*M] f32 | px[2*JB] f32 | counter
  double* mom     = (double*)d_ws;
  float*  ps      = (float*)((char*)d_ws + K2B * 5 * sizeof(double));
  float*  pc      = ps + 2 * JB * M;
  float*  px      = pc + 2 * JB * M;
  int*    counter = (int*)(px + 2 * JB);

  freq_partials<<<dim3(JB, 2), 256, 0, stream>>>(pred, target, ps, pc, px, counter);
  rank_corr<<<K2B, 256, 0, stream>>>(pred, target, ps, pc, px, mom, counter, out);
}